// Round 4
// baseline (378.891 us; speedup 1.0000x reference)
//
#include <hip/hip_runtime.h>
#include <cstddef>
#include <cstdint>

#define Bb 16
#define Uu 2048
#define Dd 512
#define BU (Bb*Uu)

typedef short bf16x8 __attribute__((ext_vector_type(8)));
typedef float f32x4 __attribute__((ext_vector_type(4)));

#define ROW_BYTES 208                 // 96 bf16 payload (h32,m32,l32) + 16B pad
#define B_OFF 27040                   // A region: 130*208
#define BSLICE 26624                  // 128 rows * 208B
#define STEP_BYTES (512*ROW_BYTES)    // 106496 per (chunk,tap) full-N B block
#define SMEM_BYTES (B_OFF + 2*BSLICE) // 80288 -> 2 blocks/CU

__device__ __forceinline__ unsigned short f2bf(float x){
  unsigned int u = __float_as_uint(x);
  u += 0x7fff + ((u >> 16) & 1);          // RNE
  return (unsigned short)(u >> 16);
}
__device__ __forceinline__ float bf2f(unsigned short b){
  return __uint_as_float(((unsigned int)b) << 16);
}

union U16x8 { unsigned short s[8]; uint4 v; };

__device__ __forceinline__ void split3(float x, unsigned short& h, unsigned short& m, unsigned short& l){
  h = f2bf(x);
  float r1 = x - bf2f(h);
  m = f2bf(r1);
  float r2 = r1 - bf2f(m);
  l = f2bf(r2);
}

// ---------------- pack conv_w -> Bpack[step=(chunk*3+tap)][n(512)][208B: bh32|bm32|bl32|pad]
__global__ __launch_bounds__(256) void pack_b_kernel(const float* __restrict__ conv_w,
                                                     char* __restrict__ Bpack){
  int idx = blockIdx.x * 256 + threadIdx.x;    // < 48*2048
  int step = idx >> 11;
  int rem = idx & 2047;
  int n = rem >> 2, u = rem & 3;
  int chunk = step / 3, tap = step - chunk * 3;
  int c0 = chunk * 32 + u * 8;
  U16x8 H, M, L;
  #pragma unroll
  for (int j = 0; j < 8; ++j){
    float w = conv_w[((size_t)n * Dd + (c0 + j)) * 3 + tap];
    split3(w, H.s[j], M.s[j], L.s[j]);
  }
  char* dst = Bpack + (size_t)step * STEP_BYTES + n * ROW_BYTES + u * 16;
  *(uint4*)(dst)       = H.v;
  *(uint4*)(dst + 64)  = M.v;
  *(uint4*)(dst + 128) = L.v;
}

// ---------------- helpers
__device__ __forceinline__ void stage_A_direct(char* smem, const float* __restrict__ xsb,
                                               int u0, int c0, int tid){
  #pragma unroll
  for (int it = 0; it < 2; ++it){
    if (it == 0 || tid < 8){
      int t = tid + it * 512;                 // 520 tasks: 130 rows x 4 col-groups
      int r = t >> 2, cg = t & 3;
      int uu = u0 - 1 + r;
      float x[8];
      if (uu >= 0 && uu < Uu){
        const float* p = xsb + (size_t)uu * Dd + c0 + cg * 8;
        float4 a = *(const float4*)p;
        float4 b = *(const float4*)(p + 4);
        x[0]=a.x; x[1]=a.y; x[2]=a.z; x[3]=a.w; x[4]=b.x; x[5]=b.y; x[6]=b.z; x[7]=b.w;
      } else {
        #pragma unroll
        for (int j = 0; j < 8; ++j) x[j] = 0.f;
      }
      U16x8 H, M, L;
      #pragma unroll
      for (int j = 0; j < 8; ++j) split3(x[j], H.s[j], M.s[j], L.s[j]);
      char* dst = smem + r * ROW_BYTES + cg * 16;
      *(uint4*)(dst)       = H.v;
      *(uint4*)(dst + 64)  = M.v;
      *(uint4*)(dst + 128) = L.v;
    }
  }
}

// copy one 26624B B-slice (26 x 1024B groups) via global_load_lds width-16
__device__ __forceinline__ void stage_slice(char* ldsB, const char* __restrict__ src,
                                            int lane, int wv){
  for (int g = wv; g < 26; g += 8){
    __builtin_amdgcn_global_load_lds(
        (const __attribute__((address_space(1))) unsigned int*)(src + g * 1024 + lane * 16),
        (__attribute__((address_space(3))) unsigned int*)(ldsB + g * 1024), 16, 0, 0);
  }
}

__device__ __forceinline__ bf16x8 ldfrag(const char* p){
  return __builtin_bit_cast(bf16x8, *(const uint4*)p);
}

// ---------------- conv GEMM: 128x128 block tile, 2 blocks/CU, 2-phase pipeline
__global__ __launch_bounds__(512, 4) void conv_mfma_kernel(
    const float* __restrict__ xs, const char* __restrict__ Bpack,
    float* __restrict__ partial)
{
  __shared__ __align__(16) char smem[SMEM_BYTES];
  const int tid = threadIdx.x;
  const int lane = tid & 63, wv = tid >> 6;
  const int wm = wv & 3;                      // 4 M-groups of 32 rows
  const int wn = wv >> 2;                     // 2 N-groups of 64 cols
  const int cs = blockIdx.x >> 8;             // col slice 0..3 (128 cols)
  const int bt = blockIdx.x & 255;
  const int b = bt >> 4, ut = bt & 15;
  const int u0 = ut * 128;
  const float* xsb = xs + (size_t)b * Uu * Dd;
  const int li = lane & 15, lg = lane >> 4;

  f32x4 acc[2][4];
  #pragma unroll
  for (int m = 0; m < 2; ++m)
    #pragma unroll
    for (int n = 0; n < 4; ++n){
      f32x4 z = {0.f, 0.f, 0.f, 0.f};
      acc[m][n] = z;
    }

  // prologue
  stage_A_direct(smem, xsb, u0, 0, tid);
  stage_slice(smem + B_OFF, Bpack + cs * BSLICE, lane, wv);
  __syncthreads();

  for (int chunk = 0; chunk < 16; ++chunk){
    const bool more = (chunk < 15);
    #pragma unroll
    for (int tap = 0; tap < 3; ++tap){
      const int p = chunk * 3 + tap;
      const int buf = p & 1;

      // 1. stage next phase's B slice into the other buffer
      if (p < 47)
        stage_slice(smem + B_OFF + (buf ^ 1) * BSLICE,
                    Bpack + (size_t)(p + 1) * STEP_BYTES + cs * BSLICE, lane, wv);

      // 2. A-prefetch (next chunk) issued before MFMA cluster
      float4 apf0, apf1, apf2, apf3;
      int ar_ = 0, acg_ = 0;
      if (tap == 2 && more){
        int c0n = (chunk + 1) * 32;
        ar_ = tid >> 2; acg_ = tid & 3;
        int uu = u0 - 1 + ar_;
        if (uu >= 0 && uu < Uu){
          const float* pp = xsb + (size_t)uu * Dd + c0n + acg_ * 8;
          apf0 = *(const float4*)pp;
          apf1 = *(const float4*)(pp + 4);
        } else {
          apf0 = make_float4(0.f,0.f,0.f,0.f); apf1 = apf0;
        }
        apf2 = make_float4(0.f,0.f,0.f,0.f); apf3 = apf2;
        if (tid < 8){
          int t2 = 512 + tid;
          int r2 = t2 >> 2, cg2 = t2 & 3;
          int uu2 = u0 - 1 + r2;
          if (uu2 >= 0 && uu2 < Uu){
            const float* p2 = xsb + (size_t)uu2 * Dd + c0n + cg2 * 8;
            apf2 = *(const float4*)p2;
            apf3 = *(const float4*)(p2 + 4);
          }
        }
      }

      // 3. A fragments (tap-shifted rows)
      bf16x8 a[2][3];
      #pragma unroll
      for (int m = 0; m < 2; ++m){
        const char* ar = smem + (size_t)(wm * 32 + m * 16 + li + tap) * ROW_BYTES + lg * 16;
        a[m][0] = ldfrag(ar);
        a[m][1] = ldfrag(ar + 64);
        a[m][2] = ldfrag(ar + 128);
      }

      // 4. B fragments + MFMA (6-pass split product)
      const char* bbase = smem + B_OFF + buf * BSLICE;
      #pragma unroll
      for (int n = 0; n < 4; ++n){
        const char* br = bbase + (size_t)(wn * 64 + n * 16 + li) * ROW_BYTES + lg * 16;
        bf16x8 bh = ldfrag(br);
        bf16x8 bm = ldfrag(br + 64);
        bf16x8 bl = ldfrag(br + 128);
        #pragma unroll
        for (int m = 0; m < 2; ++m){
          acc[m][n] = __builtin_amdgcn_mfma_f32_16x16x32_bf16(a[m][0], bh, acc[m][n], 0, 0, 0); // hh
          acc[m][n] = __builtin_amdgcn_mfma_f32_16x16x32_bf16(a[m][1], bh, acc[m][n], 0, 0, 0); // mh
          acc[m][n] = __builtin_amdgcn_mfma_f32_16x16x32_bf16(a[m][0], bm, acc[m][n], 0, 0, 0); // hm
          acc[m][n] = __builtin_amdgcn_mfma_f32_16x16x32_bf16(a[m][0], bl, acc[m][n], 0, 0, 0); // hl
          acc[m][n] = __builtin_amdgcn_mfma_f32_16x16x32_bf16(a[m][2], bh, acc[m][n], 0, 0, 0); // lh
          acc[m][n] = __builtin_amdgcn_mfma_f32_16x16x32_bf16(a[m][1], bm, acc[m][n], 0, 0, 0); // mm
        }
      }

      // 5. phase end: on tap2 also rewrite A for next chunk (barrier-separated)
      if (tap == 2 && more){
        __syncthreads();                       // all A reads of this chunk done
        U16x8 H, M, L;
        float x[8];
        x[0]=apf0.x; x[1]=apf0.y; x[2]=apf0.z; x[3]=apf0.w;
        x[4]=apf1.x; x[5]=apf1.y; x[6]=apf1.z; x[7]=apf1.w;
        #pragma unroll
        for (int jj = 0; jj < 8; ++jj) split3(x[jj], H.s[jj], M.s[jj], L.s[jj]);
        char* dst = smem + ar_ * ROW_BYTES + acg_ * 16;
        *(uint4*)(dst)       = H.v;
        *(uint4*)(dst + 64)  = M.v;
        *(uint4*)(dst + 128) = L.v;
        if (tid < 8){
          int t2 = 512 + tid;
          int r2 = t2 >> 2, cg2 = t2 & 3;
          float y[8];
          y[0]=apf2.x; y[1]=apf2.y; y[2]=apf2.z; y[3]=apf2.w;
          y[4]=apf3.x; y[5]=apf3.y; y[6]=apf3.z; y[7]=apf3.w;
          #pragma unroll
          for (int jj = 0; jj < 8; ++jj) split3(y[jj], H.s[jj], M.s[jj], L.s[jj]);
          char* dst2 = smem + r2 * ROW_BYTES + cg2 * 16;
          *(uint4*)(dst2)       = H.v;
          *(uint4*)(dst2 + 64)  = M.v;
          *(uint4*)(dst2 + 128) = L.v;
        }
        __syncthreads();
      } else {
        __syncthreads();
      }
    }
  }

  // ---- epilogue: relu(h+conv_b)*lin_w partial dot over this block's 128 cols
  // conv_b/lin_w loaded via global (small, L2-resident)
  extern __shared__ char dummy[];              // (unused; silence nothing)
  float* pbuf = (float*)smem;                  // [128 frames][2 wn]
  {
    // need conv_b/lin_w pointers: passed via constant globals below
  }
  // NOTE: conv_b/lin_w accessed through the extra params appended to partial:
  // we smuggle them via partial pointer arithmetic is ugly; instead they are
  // re-declared as kernel params in the real signature above. (see launch)
  // -- actual epilogue implemented in epilogue section of launch wrapper --
  // (kept inline here:)
  // This block intentionally empty; real epilogue below.
  // (The compiler removes it.)
  (void)pbuf;
}

// Epilogue could not read conv_b/lin_w in the kernel above without params —
// so the real conv kernel used is this one (with full signature).
__global__ __launch_bounds__(512, 4) void conv_mfma_full_kernel(
    const float* __restrict__ xs, const char* __restrict__ Bpack,
    const float* __restrict__ conv_b, const float* __restrict__ lin_w,
    float* __restrict__ partial)
{
  __shared__ __align__(16) char smem[SMEM_BYTES];
  const int tid = threadIdx.x;
  const int lane = tid & 63, wv = tid >> 6;
  const int wm = wv & 3;
  const int wn = wv >> 2;
  const int cs = blockIdx.x >> 8;
  const int bt = blockIdx.x & 255;
  const int b = bt >> 4, ut = bt & 15;
  const int u0 = ut * 128;
  const float* xsb = xs + (size_t)b * Uu * Dd;
  const int li = lane & 15, lg = lane >> 4;

  f32x4 acc[2][4];
  #pragma unroll
  for (int m = 0; m < 2; ++m)
    #pragma unroll
    for (int n = 0; n < 4; ++n){
      f32x4 z = {0.f, 0.f, 0.f, 0.f};
      acc[m][n] = z;
    }

  stage_A_direct(smem, xsb, u0, 0, tid);
  stage_slice(smem + B_OFF, Bpack + cs * BSLICE, lane, wv);
  __syncthreads();

  for (int chunk = 0; chunk < 16; ++chunk){
    const bool more = (chunk < 15);
    #pragma unroll
    for (int tap = 0; tap < 3; ++tap){
      const int p = chunk * 3 + tap;
      const int buf = p & 1;

      if (p < 47)
        stage_slice(smem + B_OFF + (buf ^ 1) * BSLICE,
                    Bpack + (size_t)(p + 1) * STEP_BYTES + cs * BSLICE, lane, wv);

      float4 apf0, apf1, apf2, apf3;
      int ar_ = 0, acg_ = 0;
      if (tap == 2 && more){
        int c0n = (chunk + 1) * 32;
        ar_ = tid >> 2; acg_ = tid & 3;
        int uu = u0 - 1 + ar_;
        if (uu >= 0 && uu < Uu){
          const float* pp = xsb + (size_t)uu * Dd + c0n + acg_ * 8;
          apf0 = *(const float4*)pp;
          apf1 = *(const float4*)(pp + 4);
        } else {
          apf0 = make_float4(0.f,0.f,0.f,0.f); apf1 = apf0;
        }
        apf2 = make_float4(0.f,0.f,0.f,0.f); apf3 = apf2;
        if (tid < 8){
          int t2 = 512 + tid;
          int r2 = t2 >> 2, cg2 = t2 & 3;
          int uu2 = u0 - 1 + r2;
          if (uu2 >= 0 && uu2 < Uu){
            const float* p2 = xsb + (size_t)uu2 * Dd + c0n + cg2 * 8;
            apf2 = *(const float4*)p2;
            apf3 = *(const float4*)(p2 + 4);
          }
        }
      }

      bf16x8 a[2][3];
      #pragma unroll
      for (int m = 0; m < 2; ++m){
        const char* ar = smem + (size_t)(wm * 32 + m * 16 + li + tap) * ROW_BYTES + lg * 16;
        a[m][0] = ldfrag(ar);
        a[m][1] = ldfrag(ar + 64);
        a[m][2] = ldfrag(ar + 128);
      }

      const char* bbase = smem + B_OFF + buf * BSLICE;
      #pragma unroll
      for (int n = 0; n < 4; ++n){
        const char* br = bbase + (size_t)(wn * 64 + n * 16 + li) * ROW_BYTES + lg * 16;
        bf16x8 bh = ldfrag(br);
        bf16x8 bm = ldfrag(br + 64);
        bf16x8 bl = ldfrag(br + 128);
        #pragma unroll
        for (int m = 0; m < 2; ++m){
          acc[m][n] = __builtin_amdgcn_mfma_f32_16x16x32_bf16(a[m][0], bh, acc[m][n], 0, 0, 0);
          acc[m][n] = __builtin_amdgcn_mfma_f32_16x16x32_bf16(a[m][1], bh, acc[m][n], 0, 0, 0);
          acc[m][n] = __builtin_amdgcn_mfma_f32_16x16x32_bf16(a[m][0], bm, acc[m][n], 0, 0, 0);
          acc[m][n] = __builtin_amdgcn_mfma_f32_16x16x32_bf16(a[m][0], bl, acc[m][n], 0, 0, 0);
          acc[m][n] = __builtin_amdgcn_mfma_f32_16x16x32_bf16(a[m][2], bh, acc[m][n], 0, 0, 0);
          acc[m][n] = __builtin_amdgcn_mfma_f32_16x16x32_bf16(a[m][1], bm, acc[m][n], 0, 0, 0);
        }
      }

      if (tap == 2 && more){
        __syncthreads();
        U16x8 H, M, L;
        float x[8];
        x[0]=apf0.x; x[1]=apf0.y; x[2]=apf0.z; x[3]=apf0.w;
        x[4]=apf1.x; x[5]=apf1.y; x[6]=apf1.z; x[7]=apf1.w;
        #pragma unroll
        for (int jj = 0; jj < 8; ++jj) split3(x[jj], H.s[jj], M.s[jj], L.s[jj]);
        char* dst = smem + ar_ * ROW_BYTES + acg_ * 16;
        *(uint4*)(dst)       = H.v;
        *(uint4*)(dst + 64)  = M.v;
        *(uint4*)(dst + 128) = L.v;
        if (tid < 8){
          int t2 = 512 + tid;
          int r2 = t2 >> 2, cg2 = t2 & 3;
          float y[8];
          y[0]=apf2.x; y[1]=apf2.y; y[2]=apf2.z; y[3]=apf2.w;
          y[4]=apf3.x; y[5]=apf3.y; y[6]=apf3.z; y[7]=apf3.w;
          #pragma unroll
          for (int jj = 0; jj < 8; ++jj) split3(y[jj], H.s[jj], M.s[jj], L.s[jj]);
          char* dst2 = smem + r2 * ROW_BYTES + cg2 * 16;
          *(uint4*)(dst2)       = H.v;
          *(uint4*)(dst2 + 64)  = M.v;
          *(uint4*)(dst2 + 128) = L.v;
        }
        __syncthreads();
      } else {
        __syncthreads();
      }
    }
  }

  // ---- epilogue: partial dot over this block's 128 cols
  float* pbuf = (float*)smem;                  // [128 frames][2]
  #pragma unroll
  for (int m = 0; m < 2; ++m){
    float s0 = 0.f, s1 = 0.f, s2 = 0.f, s3 = 0.f;
    #pragma unroll
    for (int n = 0; n < 4; ++n){
      int col = cs * 128 + wn * 64 + n * 16 + li;
      float cb = conv_b[col], lw = lin_w[col];
      f32x4 v = acc[m][n];
      float h;
      h = v[0] + cb; h = h > 0.f ? h : 0.f; s0 += h * lw;
      h = v[1] + cb; h = h > 0.f ? h : 0.f; s1 += h * lw;
      h = v[2] + cb; h = h > 0.f ? h : 0.f; s2 += h * lw;
      h = v[3] + cb; h = h > 0.f ? h : 0.f; s3 += h * lw;
    }
    #pragma unroll
    for (int msk = 1; msk < 16; msk <<= 1){
      s0 += __shfl_xor(s0, msk); s1 += __shfl_xor(s1, msk);
      s2 += __shfl_xor(s2, msk); s3 += __shfl_xor(s3, msk);
    }
    if (li == 0){
      int fr = wm * 32 + m * 16 + lg * 4;
      pbuf[(fr + 0) * 2 + wn] = s0;
      pbuf[(fr + 1) * 2 + wn] = s1;
      pbuf[(fr + 2) * 2 + wn] = s2;
      pbuf[(fr + 3) * 2 + wn] = s3;
    }
  }
  __syncthreads();
  if (tid < 128){
    float pv = pbuf[tid * 2] + pbuf[tid * 2 + 1];
    partial[(size_t)cs * BU + (size_t)b * Uu + u0 + tid] = pv;
  }
}

// ---------------- alpha combine: sigmoid(sum partials + lin_b), mask, psums
__global__ __launch_bounds__(256) void alpha_kernel(
    const float* __restrict__ partial, const float* __restrict__ lin_b,
    const int* __restrict__ xlens,
    float* __restrict__ alpha, float* __restrict__ psums)
{
  int idx = blockIdx.x * 256 + threadIdx.x;
  int b = idx >> 11;
  int u = idx & 2047;
  float v = lin_b[0];
  #pragma unroll
  for (int csi = 0; csi < 4; ++csi) v += partial[(size_t)csi * BU + idx];
  float a = 1.f / (1.f + expf(-v));
  if (u >= xlens[b]) a = 0.f;
  alpha[idx] = a;
  float s = a;
  #pragma unroll
  for (int m = 1; m < 64; m <<= 1) s += __shfl_xor(s, m);
  if ((threadIdx.x & 63) == 0) psums[(b << 5) + (u >> 6)] = s;
}

// ---------------- sequential faithful scan (one wave per batch) — unchanged (passed)
__global__ __launch_bounds__(64) void scan_kernel(
    const float* __restrict__ alpha, const float* __restrict__ psums,
    const int* __restrict__ xlens, const int* __restrict__ ylens,
    float* __restrict__ wA, float* __restrict__ wB,
    int* __restrict__ fire_pos, int* __restrict__ nf,
    float* __restrict__ out_sum)
{
  int b = blockIdx.x;
  int lane = threadIdx.x;
  float ps = (lane < 32) ? psums[(b << 5) + lane] : 0.f;
  #pragma unroll
  for (int m = 1; m < 32; m <<= 1) ps += __shfl_xor(ps, m);
  float sa = __shfl(ps, 0);
  float beta = sa / (float)ylens[b] - 1e-4f;
  int xl = xlens[b];
  if (lane == 0) out_sum[b] = sa;

  const float* ab = alpha + (size_t)b * Uu;
  float prev = 0.f;
  int cnt = 0;
  for (int u0 = 0; u0 < Uu; u0 += 64) {
    if (u0 >= xl) break;
    float val = ab[u0 + lane];
    float mywa = 0.f, mywb = 0.f;
    float a_cur = __shfl(val, 0);
    #pragma unroll 4
    for (int i = 0; i < 64; ++i) {
      float a_next = __shfl(val, (i + 1) & 63);
      float nw = prev + a_cur;
      float left = beta - prev;
      float right = nw - beta;
      bool fired = nw >= beta;
      if (lane == i) { mywa = left; mywb = right; }
      if (fired) {
        if (lane == 0) fire_pos[(b << 11) + cnt] = u0 + i;
        ++cnt;
      }
      prev = fired ? right : nw;
      a_cur = a_next;
    }
    wA[(size_t)b * Uu + u0 + lane] = mywa;
    wB[(size_t)b * Uu + u0 + lane] = mywb;
  }
  if (lane == 0) nf[b] = cnt;
}

// ---------------- segmented gather -> h_cif — unchanged (passed)
__global__ __launch_bounds__(512) void gather_kernel(
    const float* __restrict__ xs, const float* __restrict__ wA, const float* __restrict__ wB,
    const int* __restrict__ fire_pos, const int* __restrict__ nf,
    float* __restrict__ out, int umax)
{
  int t = blockIdx.x, b = blockIdx.y;
  int tid = threadIdx.x;
  float* o = out + ((size_t)b * umax + t) * Dd;
  int n = nf[b];
  if (t >= n) { o[tid] = 0.f; return; }
  int start = (t == 0) ? 0 : fire_pos[(b << 11) + t - 1];
  int end = fire_pos[(b << 11) + t];
  const float* xb = xs + (size_t)b * Uu * Dd;
  float acc = 0.f;
  for (int u = start; u <= end; ++u) {
    float w = (t > 0 && u == start) ? wB[(size_t)b * Uu + u] : wA[(size_t)b * Uu + u];
    acc += w * xb[(size_t)u * Dd + tid];
  }
  o[tid] = acc;
}

extern "C" void kernel_launch(void* const* d_in, const int* in_sizes, int n_in,
                              void* d_out, int out_size, void* d_ws, size_t ws_size,
                              hipStream_t stream) {
  const float* xs     = (const float*)d_in[0];
  const int*   xlens  = (const int*)d_in[1];
  const int*   ylens  = (const int*)d_in[2];
  const float* conv_w = (const float*)d_in[3];
  const float* conv_b = (const float*)d_in[4];
  const float* lin_w  = (const float*)d_in[5];
  const float* lin_b  = (const float*)d_in[6];
  float* out = (float*)d_out;
  int umax = (out_size - Bb) / (Bb * Dd);

  char* ws = (char*)d_ws;
  char*  Bpack    = ws;                                  // 48*106496 = 5,111,808
  float* partial  = (float*)(ws + 48 * (size_t)STEP_BYTES);  // 4*BU*4 = 512KB
  float* alpha    = partial + 4 * BU;
  float* wAv      = alpha + BU;
  float* wBv      = wAv + BU;
  int*   fire_pos = (int*)(wBv + BU);
  float* psums    = (float*)(fire_pos + BU);
  int*   nf       = (int*)(psums + 512);

  pack_b_kernel<<<(48 * 2048) / 256, 256, 0, stream>>>(conv_w, Bpack);
  conv_mfma_full_kernel<<<1024, 512, 0, stream>>>(xs, Bpack, conv_b, lin_w, partial);
  alpha_kernel<<<BU / 256, 256, 0, stream>>>(partial, lin_b, xlens, alpha, psums);
  scan_kernel<<<Bb, 64, 0, stream>>>(alpha, psums, xlens, ylens, wAv, wBv, fire_pos, nf,
                                     out + (size_t)Bb * umax * Dd);
  if (umax > 0)
    gather_kernel<<<dim3(umax, Bb), 512, 0, stream>>>(xs, wAv, wBv, fire_pos, nf, out, umax);
}